// Round 1
// baseline (17.088 us; speedup 1.0000x reference)
//
#include <hip/hip_runtime.h>
#include <math.h>

// Exact reduction of the 24-qubit circuit to a 5-qubit (32x32 real) density
// matrix via light-cone tracing:
//  - layer1: 12 disjoint pairs, partner traced out (kept qubit is CX target)
//  - layer2: 6 disjoint pairs of mixed states, control traced out
//  - cx(13,10) fold, then exact product state of qubits {2,5,10,18,21}
//  - remaining 19 RY + 7 CX applied to the 32x32 DM; <Z> from diagonal.
// DM bit map: wire 2->bit0, 5->bit1, 10->bit2, 18->bit3, 21->bit4.

__device__ __forceinline__ void ry_dm(float& a, float& b, float& d, float c, float s) {
    // rho' = U rho U^T, U = [[c,-s],[s,c]], rho = [[a,b],[b,d]]
    float na = c*c*a - 2.0f*c*s*b + s*s*d;
    float nb = c*s*(a - d) + (c*c - s*s)*b;
    float nd = s*s*a + 2.0f*c*s*b + c*c*d;
    a = na; b = nb; d = nd;
}

__global__ __launch_bounds__(256) void nodenet_dm_kernel(
    const float* __restrict__ X, const float* __restrict__ e,
    const float* __restrict__ Ri, const float* __restrict__ Ro,
    const float* __restrict__ th, float* __restrict__ out)
{
    const int n = blockIdx.x;   // node
    const int t = threadIdx.x;

    __shared__ float M[24];                // per-node angles
    __shared__ float ra[6], rb[6], rd[6];  // single-qubit DMs {2,5,10,13,18,21}
    __shared__ float dm[2][32][33];        // ping-pong 5-qubit DM (padded)

    // ---- angles M = [mi | mo | X] ----
    if (t < 8) {
        float acc = 0.0f;
        for (int E2 = 0; E2 < 16; ++E2) {
            float bo = 0.0f;
            for (int m = 0; m < 4; ++m) bo += Ro[m*16 + E2] * X[m*8 + t];
            acc += Ri[n*16 + E2] * e[E2] * bo;
        }
        M[t] = acc;                         // mi[n][t]
    } else if (t < 16) {
        const int dcol = t - 8;
        float acc = 0.0f;
        for (int E2 = 0; E2 < 16; ++E2) {
            float bi = 0.0f;
            for (int m = 0; m < 4; ++m) bi += Ri[m*16 + E2] * X[m*8 + dcol];
            acc += Ro[n*16 + E2] * e[E2] * bi;
        }
        M[t] = acc;                         // mo[n][dcol]
    } else if (t < 24) {
        M[t] = X[n*8 + (t - 16)];
    }
    __syncthreads();

    // ---- 6 chains through layers 1-2 ----
    if (t < 6) {
        const int qT[6]   = {2, 5, 10, 13, 18, 21};  // kept qubit (layer1 target)
        const int pqT[6]  = {3, 4, 11, 12, 19, 20};  // its layer1 control partner
        const int cT[6]   = {1, 6,  9, 14, 17, 22};  // layer2 control (layer1 target)
        const int pcT[6]  = {0, 7,  8, 15, 16, 23};  // control's layer1 partner
        const int tq2T[6] = {25,26, 29, 30, 33, 34}; // layer2 RY theta idx on q
        const int tc2T[6] = {24,27, 28, 31, 32, 35}; // layer2 RY theta idx on c
        const int Q = qT[t], P = pqT[t], C = cT[t], PC = pcT[t];

        float sq, cq, sp, cp;
        sincosf(0.5f*(M[Q] + th[Q]), &sq, &cq);
        sincosf(0.5f*(M[P] + th[P]), &sp, &cp);
        float aq = cp*cp*cq*cq + sp*sp*sq*sq;   // layer1 traced DM of q
        float bq = cq*sq;
        float dq = 1.0f - aq;

        float sc, cc, spc, cpc;
        sincosf(0.5f*(M[C] + th[C]), &sc, &cc);
        sincosf(0.5f*(M[PC] + th[PC]), &spc, &cpc);
        float ac = cpc*cpc*cc*cc + spc*spc*sc*sc;  // layer1 traced DM of c
        float bc = cc*sc;
        float dc = 1.0f - ac;

        // layer2: RY on c -> only populations needed
        float s2, c2;
        sincosf(0.5f*th[tc2T[t]], &s2, &c2);
        float p0 = c2*c2*ac - 2.0f*c2*s2*bc + s2*s2*dc;

        // layer2: RY on q, then CX(c->q) with c traced: rho' = p0*rho + p1*XrhoX
        float s1, c1;
        sincosf(0.5f*th[tq2T[t]], &s1, &c1);
        ry_dm(aq, bq, dq, c1, s1);
        ra[t] = p0*aq + (1.0f - p0)*dq;
        rb[t] = bq;
        rd[t] = p0*dq + (1.0f - p0)*aq;
    }
    __syncthreads();

    // ---- fold qubit 13 into 10: ry(th38 on 10), ry(th39 on 13), cx(13,10), trace 13 ----
    if (t == 0) {
        float s38, c38, s39, c39;
        sincosf(0.5f*th[38], &s38, &c38);
        sincosf(0.5f*th[39], &s39, &c39);
        float a = ra[2], b = rb[2], d = rd[2];
        ry_dm(a, b, d, c38, s38);
        float p0 = c39*c39*ra[3] - 2.0f*c39*s39*rb[3] + s39*s39*rd[3];
        ra[2] = p0*a + (1.0f - p0)*d;
        rb[2] = b;
        rd[2] = p0*d + (1.0f - p0)*a;
    }
    __syncthreads();

    // ---- init 32x32 DM = rho2 (x) rho5 (x) rho10 (x) rho18 (x) rho21 ----
    {
        const int bmap[5] = {0, 1, 2, 4, 5};   // DM bit -> chain slot
#pragma unroll
        for (int r = 0; r < 4; ++r) {
            const int eidx = t*4 + r;
            const int i = eidx >> 5, j = eidx & 31;
            float v = 1.0f;
#pragma unroll
            for (int b = 0; b < 5; ++b) {
                const int ci = (i >> b) & 1, cj = (j >> b) & 1;
                const int ch = bmap[b];
                float f = (ci == 0) ? ((cj == 0) ? ra[ch] : rb[ch])
                                    : ((cj == 0) ? rb[ch] : rd[ch]);
                v *= f;
            }
            dm[0][i][j] = v;
        }
    }
    __syncthreads();

    // ---- remaining gates on the 5-qubit DM ----
    // ty 0 = RY(bit A, theta[B]); ty 1 = CX(ctrl bit A, tgt bit B)
    const int opsTy[26] = {0,0,1, 0,0,1, 0,0,1, 0,0,1, 0,0,1, 0,0,1, 0,0,1, 0,0,0,0,0};
    const int opsA [26] = {0,1,0, 3,4,4, 1,2,1, 2,3,2, 1,2,2, 3,4,3, 0,1,1, 0,1,2,3,4};
    const int opsB [26] = {36,37,1, 40,41,3, 42,43,2, 44,45,3, 46,47,1, 48,49,4, 50,51,0, 52,53,54,55,56};

    int cur = 0;
#pragma unroll
    for (int k = 0; k < 26; ++k) {
        float nv0, nv1, nv2, nv3;
        if (opsTy[k] == 0) {
            const int m = 1 << opsA[k];
            float s1, c1;
            sincosf(0.5f * th[opsB[k]], &s1, &c1);
#pragma unroll
            for (int r = 0; r < 4; ++r) {
                const int eidx = t*4 + r;
                const int i = eidx >> 5, j = eidx & 31;
                const int i0 = i & ~m, i1 = i | m;
                const int j0 = j & ~m, j1 = j | m;
                const float ri0 = (i & m) ? s1 : c1;
                const float ri1 = (i & m) ? c1 : -s1;
                const float rj0 = (j & m) ? s1 : c1;
                const float rj1 = (j & m) ? c1 : -s1;
                const float v = ri0*(rj0*dm[cur][i0][j0] + rj1*dm[cur][i0][j1])
                              + ri1*(rj0*dm[cur][i1][j0] + rj1*dm[cur][i1][j1]);
                if (r == 0) nv0 = v; else if (r == 1) nv1 = v; else if (r == 2) nv2 = v; else nv3 = v;
            }
        } else {
            const int mc = 1 << opsA[k], mt = 1 << opsB[k];
#pragma unroll
            for (int r = 0; r < 4; ++r) {
                const int eidx = t*4 + r;
                const int i = eidx >> 5, j = eidx & 31;
                const int ip = (i & mc) ? (i ^ mt) : i;
                const int jp = (j & mc) ? (j ^ mt) : j;
                const float v = dm[cur][ip][jp];
                if (r == 0) nv0 = v; else if (r == 1) nv1 = v; else if (r == 2) nv2 = v; else nv3 = v;
            }
        }
        {
            const int e0 = t*4;
            dm[cur^1][(e0+0) >> 5][(e0+0) & 31] = nv0;
            dm[cur^1][(e0+1) >> 5][(e0+1) & 31] = nv1;
            dm[cur^1][(e0+2) >> 5][(e0+2) & 31] = nv2;
            dm[cur^1][(e0+3) >> 5][(e0+3) & 31] = nv3;
        }
        cur ^= 1;
        __syncthreads();
    }

    // ---- measure <Z> on bits 0..4 (wires 2,5,10,18,21), out = pi*(1-ev) ----
    if (t < 5) {
        float ev = 0.0f;
        for (int i = 0; i < 32; ++i) {
            const float dg = dm[cur][i][i];
            ev += ((i >> t) & 1) ? -dg : dg;
        }
        out[n*5 + t] = 3.14159265358979f * (1.0f - ev);
    }
}

extern "C" void kernel_launch(void* const* d_in, const int* in_sizes, int n_in,
                              void* d_out, int out_size, void* d_ws, size_t ws_size,
                              hipStream_t stream) {
    const float* X  = (const float*)d_in[0];
    const float* e  = (const float*)d_in[1];
    const float* Ri = (const float*)d_in[2];
    const float* Ro = (const float*)d_in[3];
    const float* th = (const float*)d_in[4];
    float* out = (float*)d_out;

    nodenet_dm_kernel<<<4, 256, 0, stream>>>(X, e, Ri, Ro, th, out);
}

// Round 3
// 12.488 us; speedup vs baseline: 1.3684x; 1.3684x over previous
//
#include <hip/hip_runtime.h>
#include <math.h>

// Exact algebra, two stages:
//  (1) Light-cone reduction: 24-qubit circuit -> product of 5 single-qubit
//      real density matrices on wires {2,5,10,18,21}
//      (DM bit b: 0->w2, 1->w5, 2->w10, 3->w18, 4->w21).
//  (2) Mixture-of-pure-states: eigendecompose each 2x2 DM into 2 real pure
//      states -> 32 weighted product pure states. One branch per lane,
//      32-float statevector in registers, evolve through 19 RY + 7 CX,
//      weighted <Z> via shfl_xor reduction. No LDS, no barriers.
//
// Round-2 bug fixed here: in the w13->w10 fold, RY(th38) modifies the
// off-diagonal b of the wire-10 DM BEFORE the traced CX; lane 2 must commit
// the post-RY b (round 2 left rb stale -> absmax 2.375).

__device__ __forceinline__ void ry_dm(float& a, float& b, float& d, float c, float s) {
    float na = c*c*a - 2.0f*c*s*b + s*s*d;
    float nb = c*s*(a - d) + (c*c - s*s)*b;
    float nd = s*s*a + 2.0f*c*s*b + c*c*d;
    a = na; b = nb; d = nd;
}

template<int MASK>
__device__ __forceinline__ void apply_ry(float* amp, float c, float s) {
#pragma unroll
    for (int i = 0; i < 32; ++i) {
        if (!(i & MASK)) {
            float x = amp[i], y = amp[i | MASK];
            amp[i]        = c * x - s * y;
            amp[i | MASK] = s * x + c * y;
        }
    }
}

template<int MC, int MT>
__device__ __forceinline__ void apply_cx(float* amp) {
#pragma unroll
    for (int i = 0; i < 32; ++i) {
        if ((i & MC) && !(i & MT)) {
            float tmp = amp[i];
            amp[i] = amp[i | MT];
            amp[i | MT] = tmp;
        }
    }
}

__global__ __launch_bounds__(64) void nodenet_branch_kernel(
    const float* __restrict__ X, const float* __restrict__ e,
    const float* __restrict__ Ri, const float* __restrict__ Ro,
    const float* __restrict__ th, float* __restrict__ out)
{
    const int t    = threadIdx.x;            // 0..63
    const int node = blockIdx.x * 2 + (t >> 5);
    const int lig  = t & 31;                 // lane in 32-group = branch id
    const int base = t & 32;                 // group base lane within wave

    // ---- Phase A: this lane computes angle M[w] for wire w = lig (lig<24) ----
    float Mv = 0.0f;
    {
        const int w = lig;
        if (w < 8) {
            float acc = 0.0f;
            for (int E = 0; E < 16; ++E) {
                float bo = 0.0f;
                for (int m = 0; m < 4; ++m) bo += Ro[m*16 + E] * X[m*8 + w];
                acc += Ri[node*16 + E] * e[E] * bo;
            }
            Mv = acc;                                    // mi[node][w]
        } else if (w < 16) {
            const int dcol = w - 8;
            float acc = 0.0f;
            for (int E = 0; E < 16; ++E) {
                float bi = 0.0f;
                for (int m = 0; m < 4; ++m) bi += Ri[m*16 + E] * X[m*8 + dcol];
                acc += Ro[node*16 + E] * e[E] * bi;
            }
            Mv = acc;                                    // mo[node][dcol]
        } else {
            Mv = X[node*8 + ((w - 16) & 7)];             // clamped for w>=24
        }
    }

    // ---- Gate-angle sincos, one per lane: id = theta_idx - 36, ids 0..20 ----
    float gs, gc;
    {
        const int id = (lig < 21) ? lig : 0;
        sincosf(0.5f * th[36 + id], &gs, &gc);
    }

    // ---- Phase B: chains (slot ss = lane 0..5; others compute garbage) ----
    const int ss = (lig < 6) ? lig : 0;
    const int Q   = ss==0?2 : ss==1?5 : ss==2?10 : ss==3?13 : ss==4?18 : 21;
    const int P   = ss==0?3 : ss==1?4 : ss==2?11 : ss==3?12 : ss==4?19 : 20;
    const int C   = ss==0?1 : ss==1?6 : ss==2?9  : ss==3?14 : ss==4?17 : 22;
    const int PC  = ss==0?0 : ss==1?7 : ss==2?8  : ss==3?15 : ss==4?16 : 23;
    const int tq2 = ss==0?25: ss==1?26: ss==2?29 : ss==3?30 : ss==4?33 : 34;
    const int tc2 = ss==0?24: ss==1?27: ss==2?28 : ss==3?31 : ss==4?32 : 35;

    const float mq  = __shfl(Mv, base + Q);
    const float mp  = __shfl(Mv, base + P);
    const float mc  = __shfl(Mv, base + C);
    const float mpc = __shfl(Mv, base + PC);

    float ra, rb, rd;
    {
        float sq, cq, sp, cp;
        sincosf(0.5f*(mq + th[Q]), &sq, &cq);
        sincosf(0.5f*(mp + th[P]), &sp, &cp);
        float aq = cp*cp*cq*cq + sp*sp*sq*sq;
        float bq = cq*sq;
        float dq = 1.0f - aq;

        float sc, cc, spc, cpc;
        sincosf(0.5f*(mc + th[C]), &sc, &cc);
        sincosf(0.5f*(mpc + th[PC]), &spc, &cpc);
        float ac = cpc*cpc*cc*cc + spc*spc*sc*sc;
        float bc = cc*sc;
        float dc = 1.0f - ac;

        float s2, c2;
        sincosf(0.5f*th[tc2], &s2, &c2);
        float p0 = c2*c2*ac - 2.0f*c2*s2*bc + s2*s2*dc;

        float s1, c1;
        sincosf(0.5f*th[tq2], &s1, &c1);
        ry_dm(aq, bq, dq, c1, s1);
        ra = p0*aq + (1.0f - p0)*dq;
        rb = bq;
        rd = p0*dq + (1.0f - p0)*aq;
    }

    // ---- Fold slot3(w13) into slot2(w10): ry th38 on 10, ry th39 on 13, cx ----
    {
        const float c38 = __shfl(gc, base + 2), s38 = __shfl(gs, base + 2);
        const float c39 = __shfl(gc, base + 3), s39 = __shfl(gs, base + 3);
        const float a3 = __shfl(ra, base + 3);
        const float b3 = __shfl(rb, base + 3);
        const float d3 = __shfl(rd, base + 3);
        float a = ra, b = rb, d = rd;
        ry_dm(a, b, d, c38, s38);          // updates a, b, d (b matters!)
        float p0 = c39*c39*a3 - 2.0f*c39*s39*b3 + s39*s39*d3;
        float fa = p0*a + (1.0f - p0)*d;
        float fd = p0*d + (1.0f - p0)*a;
        if (lig == 2) { ra = fa; rb = b; rd = fd; }   // commit POST-RY b too
    }

    // ---- Eigendecomposition per lane (no atan2/sincos) ----
    float cph, sph, lam0;
    {
        float ad = ra - rd;
        float r  = sqrtf(ad*ad + 4.0f*rb*rb);
        lam0 = 0.5f * (1.0f + r);
        float c2p = (r > 1e-12f) ? ad / r : 1.0f;
        float s2p = (r > 1e-12f) ? 2.0f*rb / r : 0.0f;
        cph = sqrtf(fmaxf(0.0f, 0.5f*(1.0f + c2p)));
        sph = copysignf(sqrtf(fmaxf(0.0f, 0.5f*(1.0f - c2p))), s2p);
    }

    // ---- Broadcast per-DM-bit (cph, sph, lam0): slots {0,1,2,4,5} ----
    float u0[5], u1[5];
    float wgt = 1.0f;
    {
        const int slotOf[5] = {0, 1, 2, 4, 5};
#pragma unroll
        for (int b = 0; b < 5; ++b) {
            const float cb = __shfl(cph,  base + slotOf[b]);
            const float sb = __shfl(sph,  base + slotOf[b]);
            const float lb = __shfl(lam0, base + slotOf[b]);
            const int bit = (lig >> b) & 1;
            u0[b] = bit ? -sb : cb;
            u1[b] = bit ?  cb : sb;
            wgt  *= bit ? (1.0f - lb) : lb;
        }
    }

    // ---- Init product statevector (static indices only) ----
    float amp[32];
    amp[0] = 1.0f;
#pragma unroll
    for (int b = 0; b < 5; ++b) {
        const int m = 1 << b;
#pragma unroll
        for (int i = 15; i >= 0; --i) {
            if (i < m) {
                amp[i + m] = amp[i] * u1[b];
                amp[i]     = amp[i] * u0[b];
            }
        }
    }

    // ---- Gates on bits 0..4 (th idx - 36 = broadcast id) ----
    float c_, s_;
#define BC(id) do { c_ = __shfl(gc, base + (id)); s_ = __shfl(gs, base + (id)); } while (0)
    BC(0);  apply_ry<1>(amp, c_, s_);    // th36 b0
    BC(1);  apply_ry<2>(amp, c_, s_);    // th37 b1
    apply_cx<1, 2>(amp);                 // cx 0->1
    BC(4);  apply_ry<8>(amp, c_, s_);    // th40 b3
    BC(5);  apply_ry<16>(amp, c_, s_);   // th41 b4
    apply_cx<16, 8>(amp);                // cx 4->3
    BC(6);  apply_ry<2>(amp, c_, s_);    // th42 b1
    BC(7);  apply_ry<4>(amp, c_, s_);    // th43 b2
    apply_cx<2, 4>(amp);                 // cx 1->2
    BC(8);  apply_ry<4>(amp, c_, s_);    // th44 b2
    BC(9);  apply_ry<8>(amp, c_, s_);    // th45 b3
    apply_cx<4, 8>(amp);                 // cx 2->3
    BC(10); apply_ry<2>(amp, c_, s_);    // th46 b1
    BC(11); apply_ry<4>(amp, c_, s_);    // th47 b2
    apply_cx<4, 2>(amp);                 // cx 2->1
    BC(12); apply_ry<8>(amp, c_, s_);    // th48 b3
    BC(13); apply_ry<16>(amp, c_, s_);   // th49 b4
    apply_cx<8, 16>(amp);                // cx 3->4
    BC(14); apply_ry<1>(amp, c_, s_);    // th50 b0
    BC(15); apply_ry<2>(amp, c_, s_);    // th51 b1
    apply_cx<2, 1>(amp);                 // cx 1->0
    BC(16); apply_ry<1>(amp, c_, s_);    // th52
    BC(17); apply_ry<2>(amp, c_, s_);    // th53
    BC(18); apply_ry<4>(amp, c_, s_);    // th54
    BC(19); apply_ry<8>(amp, c_, s_);    // th55
    BC(20); apply_ry<16>(amp, c_, s_);   // th56
#undef BC

    // ---- Weighted <Z_b> per branch, reduce across 32 branches ----
    float ev[5] = {0.f, 0.f, 0.f, 0.f, 0.f};
#pragma unroll
    for (int i = 0; i < 32; ++i) {
        const float p = amp[i] * amp[i];
#pragma unroll
        for (int b = 0; b < 5; ++b)
            ev[b] += ((i >> b) & 1) ? -p : p;
    }
#pragma unroll
    for (int b = 0; b < 5; ++b) ev[b] *= wgt;

#pragma unroll
    for (int off = 1; off < 32; off <<= 1) {
#pragma unroll
        for (int b = 0; b < 5; ++b) ev[b] += __shfl_xor(ev[b], off);
    }

    if (lig < 5) {
        const float v = lig==0 ? ev[0] : lig==1 ? ev[1] : lig==2 ? ev[2]
                      : lig==3 ? ev[3] : ev[4];
        out[node*5 + lig] = 3.14159265358979f * (1.0f - v);
    }
}

extern "C" void kernel_launch(void* const* d_in, const int* in_sizes, int n_in,
                              void* d_out, int out_size, void* d_ws, size_t ws_size,
                              hipStream_t stream) {
    const float* X  = (const float*)d_in[0];
    const float* e  = (const float*)d_in[1];
    const float* Ri = (const float*)d_in[2];
    const float* Ro = (const float*)d_in[3];
    const float* th = (const float*)d_in[4];
    float* out = (float*)d_out;

    nodenet_branch_kernel<<<2, 64, 0, stream>>>(X, e, Ri, Ro, th, out);
}

// Round 4
// 10.870 us; speedup vs baseline: 1.5720x; 1.1489x over previous
//
#include <hip/hip_runtime.h>
#include <math.h>

// Exact algebra, two stages:
//  (1) Light-cone reduction: 24-qubit circuit -> product of 5 single-qubit
//      real density matrices on wires {2,5,10,18,21}
//      (DM bit b: 0->w2, 1->w5, 2->w10, 3->w18, 4->w21).
//  (2) Mixture-of-pure-states: eigendecompose each 2x2 DM into 2 real pure
//      states -> 32 weighted product pure states, one branch per lane.
//      Delayed-merge evolution: gates applied on the smallest tensor factor
//      that supports them; CXs folded into the product merges. Only 11 RYs
//      run at full 32-amp width. No LDS, no barriers.

__device__ __forceinline__ void ry_dm(float& a, float& b, float& d, float c, float s) {
    float na = c*c*a - 2.0f*c*s*b + s*s*d;
    float nb = c*s*(a - d) + (c*c - s*s)*b;
    float nd = s*s*a + 2.0f*c*s*b + c*c*d;
    a = na; b = nb; d = nd;
}

template<int MASK>
__device__ __forceinline__ void apply_ry(float* amp, float c, float s) {
#pragma unroll
    for (int i = 0; i < 32; ++i) {
        if (!(i & MASK)) {
            float x = amp[i], y = amp[i | MASK];
            amp[i]        = c * x - s * y;
            amp[i | MASK] = s * x + c * y;
        }
    }
}

template<int MC, int MT>
__device__ __forceinline__ void apply_cx(float* amp) {
#pragma unroll
    for (int i = 0; i < 32; ++i) {
        if ((i & MC) && !(i & MT)) {
            float tmp = amp[i];
            amp[i] = amp[i | MT];
            amp[i | MT] = tmp;
        }
    }
}

__global__ __launch_bounds__(64) void nodenet_branch_kernel(
    const float* __restrict__ X, const float* __restrict__ e,
    const float* __restrict__ Ri, const float* __restrict__ Ro,
    const float* __restrict__ th, float* __restrict__ out)
{
    const int t    = threadIdx.x;            // 0..63
    const int node = blockIdx.x * 2 + (t >> 5);
    const int lig  = t & 31;                 // lane in 32-group = branch id
    const int base = t & 32;                 // group base lane within wave

    // ---- Phase A: this lane computes angle M[w] for wire w = lig (lig<24) ----
    float Mv = 0.0f;
    {
        const int w = lig;
        if (w < 8) {
            float acc = 0.0f;
            for (int E = 0; E < 16; ++E) {
                float bo = 0.0f;
                for (int m = 0; m < 4; ++m) bo += Ro[m*16 + E] * X[m*8 + w];
                acc += Ri[node*16 + E] * e[E] * bo;
            }
            Mv = acc;                                    // mi[node][w]
        } else if (w < 16) {
            const int dcol = w - 8;
            float acc = 0.0f;
            for (int E = 0; E < 16; ++E) {
                float bi = 0.0f;
                for (int m = 0; m < 4; ++m) bi += Ri[m*16 + E] * X[m*8 + dcol];
                acc += Ro[node*16 + E] * e[E] * bi;
            }
            Mv = acc;                                    // mo[node][dcol]
        } else {
            Mv = X[node*8 + ((w - 16) & 7)];             // clamped for w>=24
        }
    }

    // ---- Gate-angle sincos, one per lane: id = theta_idx - 36, ids 0..20 ----
    float gs, gc;
    {
        const int id = (lig < 21) ? lig : 0;
        __sincosf(0.5f * th[36 + id], &gs, &gc);
    }

    // ---- Phase B: chains (slot ss = lane 0..5; others compute garbage) ----
    const int ss = (lig < 6) ? lig : 0;
    const int Q   = ss==0?2 : ss==1?5 : ss==2?10 : ss==3?13 : ss==4?18 : 21;
    const int P   = ss==0?3 : ss==1?4 : ss==2?11 : ss==3?12 : ss==4?19 : 20;
    const int C   = ss==0?1 : ss==1?6 : ss==2?9  : ss==3?14 : ss==4?17 : 22;
    const int PC  = ss==0?0 : ss==1?7 : ss==2?8  : ss==3?15 : ss==4?16 : 23;
    const int tq2 = ss==0?25: ss==1?26: ss==2?29 : ss==3?30 : ss==4?33 : 34;
    const int tc2 = ss==0?24: ss==1?27: ss==2?28 : ss==3?31 : ss==4?32 : 35;

    const float mq  = __shfl(Mv, base + Q);
    const float mp  = __shfl(Mv, base + P);
    const float mc  = __shfl(Mv, base + C);
    const float mpc = __shfl(Mv, base + PC);

    float ra, rb, rd;
    {
        float sq, cq, sp, cp;
        __sincosf(0.5f*(mq + th[Q]), &sq, &cq);
        __sincosf(0.5f*(mp + th[P]), &sp, &cp);
        float aq = cp*cp*cq*cq + sp*sp*sq*sq;
        float bq = cq*sq;
        float dq = 1.0f - aq;

        float sc, cc, spc, cpc;
        __sincosf(0.5f*(mc + th[C]), &sc, &cc);
        __sincosf(0.5f*(mpc + th[PC]), &spc, &cpc);
        float ac = cpc*cpc*cc*cc + spc*spc*sc*sc;
        float bc = cc*sc;
        float dc = 1.0f - ac;

        float s2, c2;
        __sincosf(0.5f*th[tc2], &s2, &c2);
        float p0 = c2*c2*ac - 2.0f*c2*s2*bc + s2*s2*dc;

        float s1, c1;
        __sincosf(0.5f*th[tq2], &s1, &c1);
        ry_dm(aq, bq, dq, c1, s1);
        ra = p0*aq + (1.0f - p0)*dq;
        rb = bq;
        rd = p0*dq + (1.0f - p0)*aq;
    }

    // ---- Fold slot3(w13) into slot2(w10): ry th38 on 10, ry th39 on 13, cx ----
    {
        const float c38 = __shfl(gc, base + 2), s38 = __shfl(gs, base + 2);
        const float c39 = __shfl(gc, base + 3), s39 = __shfl(gs, base + 3);
        const float a3 = __shfl(ra, base + 3);
        const float b3 = __shfl(rb, base + 3);
        const float d3 = __shfl(rd, base + 3);
        float a = ra, b = rb, d = rd;
        ry_dm(a, b, d, c38, s38);          // b matters: post-RY off-diagonal
        float p0 = c39*c39*a3 - 2.0f*c39*s39*b3 + s39*s39*d3;
        float fa = p0*a + (1.0f - p0)*d;
        float fd = p0*d + (1.0f - p0)*a;
        if (lig == 2) { ra = fa; rb = b; rd = fd; }
    }

    // ---- Eigendecomposition per lane ----
    float cph, sph, lam0;
    {
        float ad = ra - rd;
        float r  = sqrtf(ad*ad + 4.0f*rb*rb);
        lam0 = 0.5f * (1.0f + r);
        float c2p = (r > 1e-12f) ? ad / r : 1.0f;
        float s2p = (r > 1e-12f) ? 2.0f*rb / r : 0.0f;
        cph = sqrtf(fmaxf(0.0f, 0.5f*(1.0f + c2p)));
        sph = copysignf(sqrtf(fmaxf(0.0f, 0.5f*(1.0f - c2p))), s2p);
    }

    // ---- Broadcast per-DM-bit (cph, sph, lam0): slots {0,1,2,4,5} ----
    float u0[5], u1[5];
    float wgt = 1.0f;
    {
        const int slotOf[5] = {0, 1, 2, 4, 5};
#pragma unroll
        for (int b = 0; b < 5; ++b) {
            const float cb = __shfl(cph,  base + slotOf[b]);
            const float sb = __shfl(sph,  base + slotOf[b]);
            const float lb = __shfl(lam0, base + slotOf[b]);
            const int bit = (lig >> b) & 1;
            u0[b] = bit ? -sb : cb;
            u1[b] = bit ?  cb : sb;
            wgt  *= bit ? (1.0f - lb) : lb;
        }
    }

    // ---- Delayed-merge gate evolution ----
    float c_, s_;
#define BC(id) do { c_ = __shfl(gc, base + (id)); s_ = __shfl(gs, base + (id)); } while (0)

    // Stage 1: ry36(b0), ry37(b1) on 2-amp factors; merge with cx(0->1)
    BC(0); float v00 = c_*u0[0] - s_*u1[0], v01 = s_*u0[0] + c_*u1[0];
    BC(1); float v10 = c_*u0[1] - s_*u1[1], v11 = s_*u0[1] + c_*u1[1];
    // q01[i0 + 2*i1], pre-CX i1' = i1 ^ i0
    float q01_0 = v00*v10, q01_1 = v01*v11, q01_2 = v00*v11, q01_3 = v01*v10;

    // Stage 2: ry40(b3), ry41(b4); merge with cx(4->3) (pre-CX i3' = i3 ^ i4)
    BC(4); float v30 = c_*u0[3] - s_*u1[3], v31 = s_*u0[3] + c_*u1[3];
    BC(5); float v40 = c_*u0[4] - s_*u1[4], v41 = s_*u0[4] + c_*u1[4];
    // q34[i3 + 2*i4]
    float q34_0 = v30*v40, q34_1 = v31*v40, q34_2 = v31*v41, q34_3 = v30*v41;

    // Stage 3: ry42(b1) on q01; ry43(b2) on 2-amp; merge with cx(1->2)
    BC(6);
    { float x = q01_0, y = q01_2; q01_0 = c_*x - s_*y; q01_2 = s_*x + c_*y;
      x = q01_1; y = q01_3;       q01_1 = c_*x - s_*y; q01_3 = s_*x + c_*y; }
    BC(7); float v20 = c_*u0[2] - s_*u1[2], v21 = s_*u0[2] + c_*u1[2];
    // q012[i0+2*i1+4*i2] = q01[i0+2*i1] * v2[i2 ^ i1]
    float q012[8];
    q012[0] = q01_0*v20; q012[1] = q01_1*v20; q012[2] = q01_2*v21; q012[3] = q01_3*v21;
    q012[4] = q01_0*v21; q012[5] = q01_1*v21; q012[6] = q01_2*v20; q012[7] = q01_3*v20;

    // Stage 4: ry44(b2) on q012; ry45(b3) on q34; merge with cx(2->3)
    BC(8);
#pragma unroll
    for (int j = 0; j < 4; ++j) {
        float x = q012[j], y = q012[j + 4];
        q012[j] = c_*x - s_*y; q012[j + 4] = s_*x + c_*y;
    }
    BC(9);
    { float x = q34_0, y = q34_1; q34_0 = c_*x - s_*y; q34_1 = s_*x + c_*y;
      x = q34_2; y = q34_3;       q34_2 = c_*x - s_*y; q34_3 = s_*x + c_*y; }

    // amp[i0+2i1+4i2+8i3+16i4] = q012[low3] * q34[(i3^i2) + 2*i4]
    float q34a[4] = {q34_0, q34_1, q34_2, q34_3};
    float amp[32];
#pragma unroll
    for (int j = 0; j < 32; ++j) {
        const int i2 = (j >> 2) & 1, i3 = (j >> 3) & 1, i4 = (j >> 4) & 1;
        amp[j] = q012[j & 7] * q34a[(i3 ^ i2) + 2*i4];
    }

    // Remaining 32-amp gates
    BC(10); apply_ry<2>(amp, c_, s_);    // th46 b1
    BC(11); apply_ry<4>(amp, c_, s_);    // th47 b2
    apply_cx<4, 2>(amp);                 // cx 2->1
    BC(12); apply_ry<8>(amp, c_, s_);    // th48 b3
    BC(13); apply_ry<16>(amp, c_, s_);   // th49 b4
    apply_cx<8, 16>(amp);                // cx 3->4
    BC(14); apply_ry<1>(amp, c_, s_);    // th50 b0
    BC(15); apply_ry<2>(amp, c_, s_);    // th51 b1
    apply_cx<2, 1>(amp);                 // cx 1->0
    BC(16); apply_ry<1>(amp, c_, s_);    // th52
    BC(17); apply_ry<2>(amp, c_, s_);    // th53
    BC(18); apply_ry<4>(amp, c_, s_);    // th54
    BC(19); apply_ry<8>(amp, c_, s_);    // th55
    BC(20); apply_ry<16>(amp, c_, s_);   // th56
#undef BC

    // ---- Tree-structured weighted <Z_b>: shared pairwise sums ----
    float p[32];
#pragma unroll
    for (int j = 0; j < 32; ++j) p[j] = amp[j] * amp[j];

    float ev0 = 0.f, ev1 = 0.f, ev2 = 0.f, ev3 = 0.f, ev4;
    float s0[16];
#pragma unroll
    for (int i = 0; i < 16; ++i) { s0[i] = p[2*i] + p[2*i+1]; ev0 += p[2*i] - p[2*i+1]; }
    float s1v[8];
#pragma unroll
    for (int i = 0; i < 8; ++i)  { s1v[i] = s0[2*i] + s0[2*i+1]; ev1 += s0[2*i] - s0[2*i+1]; }
    float s2v[4];
#pragma unroll
    for (int i = 0; i < 4; ++i)  { s2v[i] = s1v[2*i] + s1v[2*i+1]; ev2 += s1v[2*i] - s1v[2*i+1]; }
    float s3v[2];
#pragma unroll
    for (int i = 0; i < 2; ++i)  { s3v[i] = s2v[2*i] + s2v[2*i+1]; ev3 += s2v[2*i] - s2v[2*i+1]; }
    ev4 = s3v[0] - s3v[1];

    float ev[5] = {ev0*wgt, ev1*wgt, ev2*wgt, ev3*wgt, ev4*wgt};
#pragma unroll
    for (int off = 1; off < 32; off <<= 1) {
#pragma unroll
        for (int b = 0; b < 5; ++b) ev[b] += __shfl_xor(ev[b], off);
    }

    if (lig < 5) {
        const float v = lig==0 ? ev[0] : lig==1 ? ev[1] : lig==2 ? ev[2]
                      : lig==3 ? ev[3] : ev[4];
        out[node*5 + lig] = 3.14159265358979f * (1.0f - v);
    }
}

extern "C" void kernel_launch(void* const* d_in, const int* in_sizes, int n_in,
                              void* d_out, int out_size, void* d_ws, size_t ws_size,
                              hipStream_t stream) {
    const float* X  = (const float*)d_in[0];
    const float* e  = (const float*)d_in[1];
    const float* Ri = (const float*)d_in[2];
    const float* Ro = (const float*)d_in[3];
    const float* th = (const float*)d_in[4];
    float* out = (float*)d_out;

    nodenet_branch_kernel<<<2, 64, 0, stream>>>(X, e, Ri, Ro, th, out);
}

// Round 5
// 10.449 us; speedup vs baseline: 1.6354x; 1.0403x over previous
//
#include <hip/hip_runtime.h>
#include <math.h>

// Exact algebra, two stages:
//  (1) Light-cone reduction: 24-qubit circuit -> product of 5 single-qubit
//      real density matrices on wires {2,5,10,18,21}
//      (DM bit b: 0->w2, 1->w5, 2->w10, 3->w18, 4->w21).
//  (2) Mixture-of-pure-states: eigendecompose each 2x2 DM into 2 real pure
//      states -> 32 weighted product pure states, one branch per lane.
//      Delayed-merge evolution + commutation moves: only 4 RYs run at full
//      32-amp width (th47,48,50,51). Final 5 RYs (th52-56) are folded into
//      the measurement via RY^T Z RY = cos(t) Z - sin(t) X.
//      No LDS, no barriers.

__device__ __forceinline__ void ry_dm(float& a, float& b, float& d, float c, float s) {
    float na = c*c*a - 2.0f*c*s*b + s*s*d;
    float nb = c*s*(a - d) + (c*c - s*s)*b;
    float nd = s*s*a + 2.0f*c*s*b + c*c*d;
    a = na; b = nb; d = nd;
}

template<int MASK>
__device__ __forceinline__ void apply_ry(float* amp, float c, float s) {
#pragma unroll
    for (int i = 0; i < 32; ++i) {
        if (!(i & MASK)) {
            float x = amp[i], y = amp[i | MASK];
            amp[i]        = c * x - s * y;
            amp[i | MASK] = s * x + c * y;
        }
    }
}

template<int MC, int MT>
__device__ __forceinline__ void apply_cx(float* amp) {
#pragma unroll
    for (int i = 0; i < 32; ++i) {
        if ((i & MC) && !(i & MT)) {
            float tmp = amp[i];
            amp[i] = amp[i | MT];
            amp[i | MT] = tmp;
        }
    }
}

__global__ __launch_bounds__(64) void nodenet_branch_kernel(
    const float* __restrict__ X, const float* __restrict__ e,
    const float* __restrict__ Ri, const float* __restrict__ Ro,
    const float* __restrict__ th, float* __restrict__ out)
{
    const int t    = threadIdx.x;            // 0..63
    const int node = blockIdx.x * 2 + (t >> 5);
    const int lig  = t & 31;                 // lane in 32-group = branch id
    const int base = t & 32;                 // group base lane within wave

    // ---- Phase A: this lane computes angle M[w] for wire w = lig (lig<24) ----
    float Mv = 0.0f;
    {
        const int w = lig;
        if (w < 8) {
            float acc = 0.0f;
            for (int E = 0; E < 16; ++E) {
                float bo = 0.0f;
                for (int m = 0; m < 4; ++m) bo += Ro[m*16 + E] * X[m*8 + w];
                acc += Ri[node*16 + E] * e[E] * bo;
            }
            Mv = acc;                                    // mi[node][w]
        } else if (w < 16) {
            const int dcol = w - 8;
            float acc = 0.0f;
            for (int E = 0; E < 16; ++E) {
                float bi = 0.0f;
                for (int m = 0; m < 4; ++m) bi += Ri[m*16 + E] * X[m*8 + dcol];
                acc += Ro[node*16 + E] * e[E] * bi;
            }
            Mv = acc;                                    // mo[node][dcol]
        } else {
            Mv = X[node*8 + ((w - 16) & 7)];             // clamped for w>=24
        }
    }

    // ---- Gate-angle sincos, one per lane: id = theta_idx - 36, ids 0..20 ----
    float gs, gc;
    {
        const int id = (lig < 21) ? lig : 0;
        __sincosf(0.5f * th[36 + id], &gs, &gc);
    }

    // ---- Phase B: chains (slot ss = lane 0..5; others compute garbage) ----
    const int ss = (lig < 6) ? lig : 0;
    const int Q   = ss==0?2 : ss==1?5 : ss==2?10 : ss==3?13 : ss==4?18 : 21;
    const int P   = ss==0?3 : ss==1?4 : ss==2?11 : ss==3?12 : ss==4?19 : 20;
    const int C   = ss==0?1 : ss==1?6 : ss==2?9  : ss==3?14 : ss==4?17 : 22;
    const int PC  = ss==0?0 : ss==1?7 : ss==2?8  : ss==3?15 : ss==4?16 : 23;
    const int tq2 = ss==0?25: ss==1?26: ss==2?29 : ss==3?30 : ss==4?33 : 34;
    const int tc2 = ss==0?24: ss==1?27: ss==2?28 : ss==3?31 : ss==4?32 : 35;

    const float mq  = __shfl(Mv, base + Q);
    const float mp  = __shfl(Mv, base + P);
    const float mc  = __shfl(Mv, base + C);
    const float mpc = __shfl(Mv, base + PC);

    float ra, rb, rd;
    {
        float sq, cq, sp, cp;
        __sincosf(0.5f*(mq + th[Q]), &sq, &cq);
        __sincosf(0.5f*(mp + th[P]), &sp, &cp);
        float aq = cp*cp*cq*cq + sp*sp*sq*sq;
        float bq = cq*sq;
        float dq = 1.0f - aq;

        float sc, cc, spc, cpc;
        __sincosf(0.5f*(mc + th[C]), &sc, &cc);
        __sincosf(0.5f*(mpc + th[PC]), &spc, &cpc);
        float ac = cpc*cpc*cc*cc + spc*spc*sc*sc;
        float bc = cc*sc;
        float dc = 1.0f - ac;

        float s2, c2;
        __sincosf(0.5f*th[tc2], &s2, &c2);
        float p0 = c2*c2*ac - 2.0f*c2*s2*bc + s2*s2*dc;

        float s1, c1;
        __sincosf(0.5f*th[tq2], &s1, &c1);
        ry_dm(aq, bq, dq, c1, s1);
        ra = p0*aq + (1.0f - p0)*dq;
        rb = bq;
        rd = p0*dq + (1.0f - p0)*aq;
    }

    // ---- Fold slot3(w13) into slot2(w10): ry th38 on 10, ry th39 on 13, cx ----
    {
        const float c38 = __shfl(gc, base + 2), s38 = __shfl(gs, base + 2);
        const float c39 = __shfl(gc, base + 3), s39 = __shfl(gs, base + 3);
        const float a3 = __shfl(ra, base + 3);
        const float b3 = __shfl(rb, base + 3);
        const float d3 = __shfl(rd, base + 3);
        float a = ra, b = rb, d = rd;
        ry_dm(a, b, d, c38, s38);          // b matters: post-RY off-diagonal
        float p0 = c39*c39*a3 - 2.0f*c39*s39*b3 + s39*s39*d3;
        float fa = p0*a + (1.0f - p0)*d;
        float fd = p0*d + (1.0f - p0)*a;
        if (lig == 2) { ra = fa; rb = b; rd = fd; }
    }

    // ---- Eigendecomposition per lane ----
    float cph, sph, lam0;
    {
        float ad = ra - rd;
        float r  = sqrtf(ad*ad + 4.0f*rb*rb);
        lam0 = 0.5f * (1.0f + r);
        float c2p = (r > 1e-12f) ? ad / r : 1.0f;
        float s2p = (r > 1e-12f) ? 2.0f*rb / r : 0.0f;
        cph = sqrtf(fmaxf(0.0f, 0.5f*(1.0f + c2p)));
        sph = copysignf(sqrtf(fmaxf(0.0f, 0.5f*(1.0f - c2p))), s2p);
    }

    // ---- Broadcast per-DM-bit (cph, sph, lam0): slots {0,1,2,4,5} ----
    float u0[5], u1[5];
    float wgt = 1.0f;
    {
        const int slotOf[5] = {0, 1, 2, 4, 5};
#pragma unroll
        for (int b = 0; b < 5; ++b) {
            const float cb = __shfl(cph,  base + slotOf[b]);
            const float sb = __shfl(sph,  base + slotOf[b]);
            const float lb = __shfl(lam0, base + slotOf[b]);
            const int bit = (lig >> b) & 1;
            u0[b] = bit ? -sb : cb;
            u1[b] = bit ?  cb : sb;
            wgt  *= bit ? (1.0f - lb) : lb;
        }
    }

    // ---- Delayed-merge gate evolution ----
    float c_, s_;
#define BC(id) do { c_ = __shfl(gc, base + (id)); s_ = __shfl(gs, base + (id)); } while (0)

    // Stage 1: ry36(b0), ry37(b1) on 2-amp factors; merge with cx(0->1)
    BC(0); float v00 = c_*u0[0] - s_*u1[0], v01 = s_*u0[0] + c_*u1[0];
    BC(1); float v10 = c_*u0[1] - s_*u1[1], v11 = s_*u0[1] + c_*u1[1];
    // q01[i0 + 2*i1], pre-CX i1' = i1 ^ i0
    float q01_0 = v00*v10, q01_1 = v01*v11, q01_2 = v00*v11, q01_3 = v01*v10;

    // Stage 2: ry40(b3), ry41(b4); merge with cx(4->3) (pre-CX i3' = i3 ^ i4)
    BC(4); float v30 = c_*u0[3] - s_*u1[3], v31 = s_*u0[3] + c_*u1[3];
    BC(5); float v40 = c_*u0[4] - s_*u1[4], v41 = s_*u0[4] + c_*u1[4];
    // q34[i3 + 2*i4]
    float q34_0 = v30*v40, q34_1 = v31*v40, q34_2 = v31*v41, q34_3 = v30*v41;

    // Stage 3: ry42(b1) on q01; ry43(b2) on 2-amp; merge with cx(1->2)
    BC(6);
    { float x = q01_0, y = q01_2; q01_0 = c_*x - s_*y; q01_2 = s_*x + c_*y;
      x = q01_1; y = q01_3;       q01_1 = c_*x - s_*y; q01_3 = s_*x + c_*y; }
    BC(7); float v20 = c_*u0[2] - s_*u1[2], v21 = s_*u0[2] + c_*u1[2];
    // q012[i0+2*i1+4*i2] = q01[i0+2*i1] * v2[i2 ^ i1]
    float q012[8];
    q012[0] = q01_0*v20; q012[1] = q01_1*v20; q012[2] = q01_2*v21; q012[3] = q01_3*v21;
    q012[4] = q01_0*v21; q012[5] = q01_1*v21; q012[6] = q01_2*v20; q012[7] = q01_3*v20;

    // Stage 4a: ry44(b2) on q012
    BC(8);
#pragma unroll
    for (int j = 0; j < 4; ++j) {
        float x = q012[j], y = q012[j + 4];
        q012[j] = c_*x - s_*y; q012[j + 4] = s_*x + c_*y;
    }
    // ry46(b1) MOVED pre-merge onto q012 (commutes with cx(2->3): b1 disjoint)
    BC(10);
    { float x, y;
      x = q012[0]; y = q012[2]; q012[0] = c_*x - s_*y; q012[2] = s_*x + c_*y;
      x = q012[1]; y = q012[3]; q012[1] = c_*x - s_*y; q012[3] = s_*x + c_*y;
      x = q012[4]; y = q012[6]; q012[4] = c_*x - s_*y; q012[6] = s_*x + c_*y;
      x = q012[5]; y = q012[7]; q012[5] = c_*x - s_*y; q012[7] = s_*x + c_*y; }

    // Stage 4b: ry45(b3) on q34
    BC(9);
    { float x = q34_0, y = q34_1; q34_0 = c_*x - s_*y; q34_1 = s_*x + c_*y;
      x = q34_2; y = q34_3;       q34_2 = c_*x - s_*y; q34_3 = s_*x + c_*y; }
    // ry49(b4) MOVED pre-merge onto q34 (commutes with cx(2->3), ry46/47,
    // cx(2->1), ry48 — all supports disjoint from b4)
    BC(13);
    { float x = q34_0, y = q34_2; q34_0 = c_*x - s_*y; q34_2 = s_*x + c_*y;
      x = q34_1; y = q34_3;       q34_1 = c_*x - s_*y; q34_3 = s_*x + c_*y; }

    // Merge with cx(2->3): amp[i0+2i1+4i2+8i3+16i4] = q012[low3] * q34[(i3^i2)+2*i4]
    float q34a[4] = {q34_0, q34_1, q34_2, q34_3};
    float amp[32];
#pragma unroll
    for (int j = 0; j < 32; ++j) {
        const int i2 = (j >> 2) & 1, i3 = (j >> 3) & 1, i4 = (j >> 4) & 1;
        amp[j] = q012[j & 7] * q34a[(i3 ^ i2) + 2*i4];
    }

    // Remaining 32-amp gates (4 RYs; CXs are free register renames)
    BC(11); apply_ry<4>(amp, c_, s_);    // th47 b2
    apply_cx<4, 2>(amp);                 // cx 2->1
    BC(12); apply_ry<8>(amp, c_, s_);    // th48 b3
    apply_cx<8, 16>(amp);                // cx 3->4
    BC(14); apply_ry<1>(amp, c_, s_);    // th50 b0
    BC(15); apply_ry<2>(amp, c_, s_);    // th51 b1
    apply_cx<2, 1>(amp);                 // cx 1->0

    // ---- Measurement with final RYs (th52-56) folded in:
    //      <Z_b>_final = cos(th)*<Z_b> - sin(th)*<X_b> on the pre-RY state ----
    float p[32];
#pragma unroll
    for (int j = 0; j < 32; ++j) p[j] = amp[j] * amp[j];

    // Z tree
    float z0 = 0.f, z1 = 0.f, z2 = 0.f, z3 = 0.f, z4;
    float s0[16];
#pragma unroll
    for (int i = 0; i < 16; ++i) { s0[i] = p[2*i] + p[2*i+1]; z0 += p[2*i] - p[2*i+1]; }
    float s1v[8];
#pragma unroll
    for (int i = 0; i < 8; ++i)  { s1v[i] = s0[2*i] + s0[2*i+1]; z1 += s0[2*i] - s0[2*i+1]; }
    float s2v[4];
#pragma unroll
    for (int i = 0; i < 4; ++i)  { s2v[i] = s1v[2*i] + s1v[2*i+1]; z2 += s1v[2*i] - s1v[2*i+1]; }
    float s3v[2];
#pragma unroll
    for (int i = 0; i < 2; ++i)  { s3v[i] = s2v[2*i] + s2v[2*i+1]; z3 += s2v[2*i] - s2v[2*i+1]; }
    z4 = s3v[0] - s3v[1];
    const float zv[5] = {z0, z1, z2, z3, z4};

    // X_b = 2 * sum_{i: bit b = 0} amp[i]*amp[i|m]
    float xv[5];
#pragma unroll
    for (int b = 0; b < 5; ++b) {
        const int m = 1 << b;
        float acc = 0.0f;
#pragma unroll
        for (int i = 0; i < 32; ++i)
            if (!(i & m)) acc += amp[i] * amp[i | m];
        xv[b] = 2.0f * acc;
    }

    // ev_b = wgt * ((c^2-s^2) Z_b - 2cs X_b), (c,s) = half-angle of th[52+b]
    float ev[5];
#pragma unroll
    for (int b = 0; b < 5; ++b) {
        BC(16 + b);
        ev[b] = wgt * ((c_*c_ - s_*s_) * zv[b] - 2.0f*c_*s_ * xv[b]);
    }
#undef BC

#pragma unroll
    for (int off = 1; off < 32; off <<= 1) {
#pragma unroll
        for (int b = 0; b < 5; ++b) ev[b] += __shfl_xor(ev[b], off);
    }

    if (lig < 5) {
        const float v = lig==0 ? ev[0] : lig==1 ? ev[1] : lig==2 ? ev[2]
                      : lig==3 ? ev[3] : ev[4];
        out[node*5 + lig] = 3.14159265358979f * (1.0f - v);
    }
}

extern "C" void kernel_launch(void* const* d_in, const int* in_sizes, int n_in,
                              void* d_out, int out_size, void* d_ws, size_t ws_size,
                              hipStream_t stream) {
    const float* X  = (const float*)d_in[0];
    const float* e  = (const float*)d_in[1];
    const float* Ri = (const float*)d_in[2];
    const float* Ro = (const float*)d_in[3];
    const float* th = (const float*)d_in[4];
    float* out = (float*)d_out;

    nodenet_branch_kernel<<<2, 64, 0, stream>>>(X, e, Ri, Ro, th, out);
}

// Round 6
// 9.585 us; speedup vs baseline: 1.7827x; 1.0901x over previous
//
#include <hip/hip_runtime.h>
#include <math.h>

// Exact algebra, two stages:
//  (1) Light-cone reduction: 24-qubit circuit -> product of 5 single-qubit
//      real density matrices on wires {2,5,10,18,21}
//      (DM bit b: 0->w2, 1->w5, 2->w10, 3->w18, 4->w21).
//  (2) Mixture-of-pure-states: eigendecompose each 2x2 DM into 2 real pure
//      states -> 32 weighted product pure states, one branch per lane.
//      Delayed-merge evolution + commutation moves: only 4 RYs run at full
//      32-amp width (th47,48,50,51). Final 5 RYs (th52-56) are folded into
//      the measurement via RY^T Z RY = cos(t) Z - sin(t) X.
//      No LDS, no barriers.
// Round 6: Phase A unified (pointer-select, one loop for lanes 0-15) and
// E-halved (lanes 16-31 compute the E in [8,16) partial; shfl_xor(16)
// combine) — removes ~120 serial issue slots of divergent FMA work.

__device__ __forceinline__ void ry_dm(float& a, float& b, float& d, float c, float s) {
    float na = c*c*a - 2.0f*c*s*b + s*s*d;
    float nb = c*s*(a - d) + (c*c - s*s)*b;
    float nd = s*s*a + 2.0f*c*s*b + c*c*d;
    a = na; b = nb; d = nd;
}

template<int MASK>
__device__ __forceinline__ void apply_ry(float* amp, float c, float s) {
#pragma unroll
    for (int i = 0; i < 32; ++i) {
        if (!(i & MASK)) {
            float x = amp[i], y = amp[i | MASK];
            amp[i]        = c * x - s * y;
            amp[i | MASK] = s * x + c * y;
        }
    }
}

template<int MC, int MT>
__device__ __forceinline__ void apply_cx(float* amp) {
#pragma unroll
    for (int i = 0; i < 32; ++i) {
        if ((i & MC) && !(i & MT)) {
            float tmp = amp[i];
            amp[i] = amp[i | MT];
            amp[i | MT] = tmp;
        }
    }
}

__global__ __launch_bounds__(64) void nodenet_branch_kernel(
    const float* __restrict__ X, const float* __restrict__ e,
    const float* __restrict__ Ri, const float* __restrict__ Ro,
    const float* __restrict__ th, float* __restrict__ out)
{
    const int t    = threadIdx.x;            // 0..63
    const int node = blockIdx.x * 2 + (t >> 5);
    const int lig  = t & 31;                 // lane in 32-group = branch id
    const int base = t & 32;                 // group base lane within wave

    // ---- Phase A (unified + E-halved):
    // lane role: w = lig&15 (wire 0..15), half = lig>>4 selects E in [8h, 8h+8).
    // mi[w<8] uses (outer=Ri, inner=Ro); mo[w>=8] uses (outer=Ro, inner=Ri).
    float Mv;
    {
        const int w    = lig & 15;
        const int half = lig >> 4;
        const int dcol = w & 7;
        const float* Aouter = (w < 8) ? Ri : Ro;
        const float* Ainner = (w < 8) ? Ro : Ri;
        const float x0 = X[0*8 + dcol], x1 = X[1*8 + dcol],
                    x2 = X[2*8 + dcol], x3 = X[3*8 + dcol];
        float acc = 0.0f;
        const int E0 = half * 8;
#pragma unroll
        for (int E = 0; E < 8; ++E) {
            const int Ei = E0 + E;
            float bsum = Ainner[0*16 + Ei]*x0 + Ainner[1*16 + Ei]*x1
                       + Ainner[2*16 + Ei]*x2 + Ainner[3*16 + Ei]*x3;
            acc += Aouter[node*16 + Ei] * e[Ei] * bsum;
        }
        acc += __shfl_xor(acc, 16);          // combine E-halves (lane w gets both)
        // lanes 0..15: angle mi/mo; lanes 16..23: X; lanes 24..31: clamped X
        Mv = (lig < 16) ? acc : X[node*8 + ((lig - 16) & 7)];
    }

    // ---- Gate-angle sincos, one per lane: id = theta_idx - 36, ids 0..20 ----
    float gs, gc;
    {
        const int id = (lig < 21) ? lig : 0;
        __sincosf(0.5f * th[36 + id], &gs, &gc);
    }

    // ---- Phase B: chains (slot ss = lane 0..5; others compute garbage) ----
    const int ss = (lig < 6) ? lig : 0;
    const int Q   = ss==0?2 : ss==1?5 : ss==2?10 : ss==3?13 : ss==4?18 : 21;
    const int P   = ss==0?3 : ss==1?4 : ss==2?11 : ss==3?12 : ss==4?19 : 20;
    const int C   = ss==0?1 : ss==1?6 : ss==2?9  : ss==3?14 : ss==4?17 : 22;
    const int PC  = ss==0?0 : ss==1?7 : ss==2?8  : ss==3?15 : ss==4?16 : 23;
    const int tq2 = ss==0?25: ss==1?26: ss==2?29 : ss==3?30 : ss==4?33 : 34;
    const int tc2 = ss==0?24: ss==1?27: ss==2?28 : ss==3?31 : ss==4?32 : 35;

    const float mq  = __shfl(Mv, base + Q);
    const float mp  = __shfl(Mv, base + P);
    const float mc  = __shfl(Mv, base + C);
    const float mpc = __shfl(Mv, base + PC);

    float ra, rb, rd;
    {
        float sq, cq, sp, cp;
        __sincosf(0.5f*(mq + th[Q]), &sq, &cq);
        __sincosf(0.5f*(mp + th[P]), &sp, &cp);
        float aq = cp*cp*cq*cq + sp*sp*sq*sq;
        float bq = cq*sq;
        float dq = 1.0f - aq;

        float sc, cc, spc, cpc;
        __sincosf(0.5f*(mc + th[C]), &sc, &cc);
        __sincosf(0.5f*(mpc + th[PC]), &spc, &cpc);
        float ac = cpc*cpc*cc*cc + spc*spc*sc*sc;
        float bc = cc*sc;
        float dc = 1.0f - ac;

        float s2, c2;
        __sincosf(0.5f*th[tc2], &s2, &c2);
        float p0 = c2*c2*ac - 2.0f*c2*s2*bc + s2*s2*dc;

        float s1, c1;
        __sincosf(0.5f*th[tq2], &s1, &c1);
        ry_dm(aq, bq, dq, c1, s1);
        ra = p0*aq + (1.0f - p0)*dq;
        rb = bq;
        rd = p0*dq + (1.0f - p0)*aq;
    }

    // ---- Fold slot3(w13) into slot2(w10): ry th38 on 10, ry th39 on 13, cx ----
    {
        const float c38 = __shfl(gc, base + 2), s38 = __shfl(gs, base + 2);
        const float c39 = __shfl(gc, base + 3), s39 = __shfl(gs, base + 3);
        const float a3 = __shfl(ra, base + 3);
        const float b3 = __shfl(rb, base + 3);
        const float d3 = __shfl(rd, base + 3);
        float a = ra, b = rb, d = rd;
        ry_dm(a, b, d, c38, s38);          // b matters: post-RY off-diagonal
        float p0 = c39*c39*a3 - 2.0f*c39*s39*b3 + s39*s39*d3;
        float fa = p0*a + (1.0f - p0)*d;
        float fd = p0*d + (1.0f - p0)*a;
        if (lig == 2) { ra = fa; rb = b; rd = fd; }
    }

    // ---- Eigendecomposition per lane ----
    float cph, sph, lam0;
    {
        float ad = ra - rd;
        float r  = sqrtf(ad*ad + 4.0f*rb*rb);
        lam0 = 0.5f * (1.0f + r);
        float c2p = (r > 1e-12f) ? ad / r : 1.0f;
        float s2p = (r > 1e-12f) ? 2.0f*rb / r : 0.0f;
        cph = sqrtf(fmaxf(0.0f, 0.5f*(1.0f + c2p)));
        sph = copysignf(sqrtf(fmaxf(0.0f, 0.5f*(1.0f - c2p))), s2p);
    }

    // ---- Broadcast per-DM-bit (cph, sph, lam0): slots {0,1,2,4,5} ----
    float u0[5], u1[5];
    float wgt = 1.0f;
    {
        const int slotOf[5] = {0, 1, 2, 4, 5};
#pragma unroll
        for (int b = 0; b < 5; ++b) {
            const float cb = __shfl(cph,  base + slotOf[b]);
            const float sb = __shfl(sph,  base + slotOf[b]);
            const float lb = __shfl(lam0, base + slotOf[b]);
            const int bit = (lig >> b) & 1;
            u0[b] = bit ? -sb : cb;
            u1[b] = bit ?  cb : sb;
            wgt  *= bit ? (1.0f - lb) : lb;
        }
    }

    // ---- Delayed-merge gate evolution ----
    float c_, s_;
#define BC(id) do { c_ = __shfl(gc, base + (id)); s_ = __shfl(gs, base + (id)); } while (0)

    // Stage 1: ry36(b0), ry37(b1) on 2-amp factors; merge with cx(0->1)
    BC(0); float v00 = c_*u0[0] - s_*u1[0], v01 = s_*u0[0] + c_*u1[0];
    BC(1); float v10 = c_*u0[1] - s_*u1[1], v11 = s_*u0[1] + c_*u1[1];
    // q01[i0 + 2*i1], pre-CX i1' = i1 ^ i0
    float q01_0 = v00*v10, q01_1 = v01*v11, q01_2 = v00*v11, q01_3 = v01*v10;

    // Stage 2: ry40(b3), ry41(b4); merge with cx(4->3) (pre-CX i3' = i3 ^ i4)
    BC(4); float v30 = c_*u0[3] - s_*u1[3], v31 = s_*u0[3] + c_*u1[3];
    BC(5); float v40 = c_*u0[4] - s_*u1[4], v41 = s_*u0[4] + c_*u1[4];
    // q34[i3 + 2*i4]
    float q34_0 = v30*v40, q34_1 = v31*v40, q34_2 = v31*v41, q34_3 = v30*v41;

    // Stage 3: ry42(b1) on q01; ry43(b2) on 2-amp; merge with cx(1->2)
    BC(6);
    { float x = q01_0, y = q01_2; q01_0 = c_*x - s_*y; q01_2 = s_*x + c_*y;
      x = q01_1; y = q01_3;       q01_1 = c_*x - s_*y; q01_3 = s_*x + c_*y; }
    BC(7); float v20 = c_*u0[2] - s_*u1[2], v21 = s_*u0[2] + c_*u1[2];
    // q012[i0+2*i1+4*i2] = q01[i0+2*i1] * v2[i2 ^ i1]
    float q012[8];
    q012[0] = q01_0*v20; q012[1] = q01_1*v20; q012[2] = q01_2*v21; q012[3] = q01_3*v21;
    q012[4] = q01_0*v21; q012[5] = q01_1*v21; q012[6] = q01_2*v20; q012[7] = q01_3*v20;

    // Stage 4a: ry44(b2) on q012
    BC(8);
#pragma unroll
    for (int j = 0; j < 4; ++j) {
        float x = q012[j], y = q012[j + 4];
        q012[j] = c_*x - s_*y; q012[j + 4] = s_*x + c_*y;
    }
    // ry46(b1) MOVED pre-merge onto q012 (commutes with cx(2->3): b1 disjoint)
    BC(10);
    { float x, y;
      x = q012[0]; y = q012[2]; q012[0] = c_*x - s_*y; q012[2] = s_*x + c_*y;
      x = q012[1]; y = q012[3]; q012[1] = c_*x - s_*y; q012[3] = s_*x + c_*y;
      x = q012[4]; y = q012[6]; q012[4] = c_*x - s_*y; q012[6] = s_*x + c_*y;
      x = q012[5]; y = q012[7]; q012[5] = c_*x - s_*y; q012[7] = s_*x + c_*y; }

    // Stage 4b: ry45(b3) on q34
    BC(9);
    { float x = q34_0, y = q34_1; q34_0 = c_*x - s_*y; q34_1 = s_*x + c_*y;
      x = q34_2; y = q34_3;       q34_2 = c_*x - s_*y; q34_3 = s_*x + c_*y; }
    // ry49(b4) MOVED pre-merge onto q34 (commutes with cx(2->3), ry46/47,
    // cx(2->1), ry48 — all supports disjoint from b4)
    BC(13);
    { float x = q34_0, y = q34_2; q34_0 = c_*x - s_*y; q34_2 = s_*x + c_*y;
      x = q34_1; y = q34_3;       q34_1 = c_*x - s_*y; q34_3 = s_*x + c_*y; }

    // Merge with cx(2->3): amp[i0+2i1+4i2+8i3+16i4] = q012[low3] * q34[(i3^i2)+2*i4]
    float q34a[4] = {q34_0, q34_1, q34_2, q34_3};
    float amp[32];
#pragma unroll
    for (int j = 0; j < 32; ++j) {
        const int i2 = (j >> 2) & 1, i3 = (j >> 3) & 1, i4 = (j >> 4) & 1;
        amp[j] = q012[j & 7] * q34a[(i3 ^ i2) + 2*i4];
    }

    // Remaining 32-amp gates (4 RYs; CXs are free register renames)
    BC(11); apply_ry<4>(amp, c_, s_);    // th47 b2
    apply_cx<4, 2>(amp);                 // cx 2->1
    BC(12); apply_ry<8>(amp, c_, s_);    // th48 b3
    apply_cx<8, 16>(amp);                // cx 3->4
    BC(14); apply_ry<1>(amp, c_, s_);    // th50 b0
    BC(15); apply_ry<2>(amp, c_, s_);    // th51 b1
    apply_cx<2, 1>(amp);                 // cx 1->0

    // ---- Measurement with final RYs (th52-56) folded in:
    //      <Z_b>_final = cos(th)*<Z_b> - sin(th)*<X_b> on the pre-RY state ----
    float p[32];
#pragma unroll
    for (int j = 0; j < 32; ++j) p[j] = amp[j] * amp[j];

    // Z tree
    float z0 = 0.f, z1 = 0.f, z2 = 0.f, z3 = 0.f, z4;
    float s0[16];
#pragma unroll
    for (int i = 0; i < 16; ++i) { s0[i] = p[2*i] + p[2*i+1]; z0 += p[2*i] - p[2*i+1]; }
    float s1v[8];
#pragma unroll
    for (int i = 0; i < 8; ++i)  { s1v[i] = s0[2*i] + s0[2*i+1]; z1 += s0[2*i] - s0[2*i+1]; }
    float s2v[4];
#pragma unroll
    for (int i = 0; i < 4; ++i)  { s2v[i] = s1v[2*i] + s1v[2*i+1]; z2 += s1v[2*i] - s1v[2*i+1]; }
    float s3v[2];
#pragma unroll
    for (int i = 0; i < 2; ++i)  { s3v[i] = s2v[2*i] + s2v[2*i+1]; z3 += s2v[2*i] - s2v[2*i+1]; }
    z4 = s3v[0] - s3v[1];
    const float zv[5] = {z0, z1, z2, z3, z4};

    // X_b = 2 * sum_{i: bit b = 0} amp[i]*amp[i|m]
    float xv[5];
#pragma unroll
    for (int b = 0; b < 5; ++b) {
        const int m = 1 << b;
        float acc = 0.0f;
#pragma unroll
        for (int i = 0; i < 32; ++i)
            if (!(i & m)) acc += amp[i] * amp[i | m];
        xv[b] = 2.0f * acc;
    }

    // ev_b = wgt * ((c^2-s^2) Z_b - 2cs X_b), (c,s) = half-angle of th[52+b]
    float ev[5];
#pragma unroll
    for (int b = 0; b < 5; ++b) {
        BC(16 + b);
        ev[b] = wgt * ((c_*c_ - s_*s_) * zv[b] - 2.0f*c_*s_ * xv[b]);
    }
#undef BC

#pragma unroll
    for (int off = 1; off < 32; off <<= 1) {
#pragma unroll
        for (int b = 0; b < 5; ++b) ev[b] += __shfl_xor(ev[b], off);
    }

    if (lig < 5) {
        const float v = lig==0 ? ev[0] : lig==1 ? ev[1] : lig==2 ? ev[2]
                      : lig==3 ? ev[3] : ev[4];
        out[node*5 + lig] = 3.14159265358979f * (1.0f - v);
    }
}

extern "C" void kernel_launch(void* const* d_in, const int* in_sizes, int n_in,
                              void* d_out, int out_size, void* d_ws, size_t ws_size,
                              hipStream_t stream) {
    const float* X  = (const float*)d_in[0];
    const float* e  = (const float*)d_in[1];
    const float* Ri = (const float*)d_in[2];
    const float* Ro = (const float*)d_in[3];
    const float* th = (const float*)d_in[4];
    float* out = (float*)d_out;

    nodenet_branch_kernel<<<2, 64, 0, stream>>>(X, e, Ri, Ro, th, out);
}